// Round 2
// baseline (300.399 us; speedup 1.0000x reference)
//
#include <hip/hip_runtime.h>
#include <math.h>

#define BB 64
#define SS 2048
#define HH 1024
#define NCHUNK 32
#define CHUNK 64   // SS / NCHUNK
#define RPW 16     // rows per wave = CHUNK / 4 waves

typedef float f4 __attribute__((ext_vector_type(4)));

// ws layout (floats):
#define QP_OFF   0                            // q partials   [4][64][1024]
#define PCTX_OFF (QP_OFF + 4 * BB * HH)       // part_ctx     [64][32][1024]
#define PML_OFF  (PCTX_OFF + BB * NCHUNK * HH)// part_ml      [64][32][2]
#define CTXF_OFF (PML_OFF + BB * NCHUNK * 2)  // ctx_final    [64][1024]
#define OP_OFF   (CTXF_OFF + BB * HH)         // out partials [8][64][1024]
// total ~= 2.95M floats ~= 11.8 MB

// ---------------------------------------------------------------------------
// K-split GEMM, 16 output cols per block: out_part[split][b][col] =
//   sum_{j in split's K-range} A(b,j) * W[col*KTOT + j]
// A(b,j) = j<1024 ? A0[b*1024+j] : A1[b*1024+(j-1024)]
// grid (64 col-tiles, KS splits), 256 threads. Chunk = 128 floats, CPB chunks
// per split. LDS: A 32KB + W 8KB.
// ---------------------------------------------------------------------------
__global__ __launch_bounds__(256) void gemm_cols16(
    const float* __restrict__ A0, const float* __restrict__ A1,
    const float* __restrict__ W, float* __restrict__ out_part,
    int KTOT, int CPB)
{
    __shared__ f4 A_lds[64 * 32];  // [row][granule^row]
    __shared__ f4 W_lds[16 * 32];
    const int t    = threadIdx.x;
    const int tile = blockIdx.x;
    const int spl  = blockIdx.y;
    const int b    = t & 63;
    const int cg   = t >> 6;
    float acc[4] = {0.f, 0.f, 0.f, 0.f};

    for (int kk = 0; kk < CPB; ++kk) {
        const int kc = spl * CPB + kk;  // global 128-float chunk index
        #pragma unroll
        for (int i = 0; i < 8; ++i) {   // stage A [64][128]
            const int idx = t + i * 256;
            const int row = idx >> 5, g = idx & 31;
            const float* src = (kc < 8) ? (A0 + row * 1024 + kc * 128)
                                        : (A1 + row * 1024 + (kc - 8) * 128);
            A_lds[row * 32 + (g ^ (row & 31))] = *(const f4*)(src + g * 4);
        }
        #pragma unroll
        for (int i = 0; i < 2; ++i) {   // stage W [16][128]
            const int idx = t + i * 256;
            const int r = idx >> 5, g = idx & 31;
            W_lds[r * 32 + g] =
                *(const f4*)(W + (size_t)(tile * 16 + r) * KTOT + kc * 128 + g * 4);
        }
        __syncthreads();
        #pragma unroll 8
        for (int j4 = 0; j4 < 32; ++j4) {
            const f4 a = A_lds[b * 32 + (j4 ^ (b & 31))];
            #pragma unroll
            for (int cix = 0; cix < 4; ++cix) {
                const f4 wv = W_lds[(cg * 4 + cix) * 32 + j4];
                acc[cix] += a.x * wv.x + a.y * wv.y + a.z * wv.z + a.w * wv.w;
            }
        }
        __syncthreads();
    }
    float* op = out_part + ((size_t)spl * BB + b) * HH + tile * 16 + cg * 4;
    *(f4*)op = (f4){acc[0], acc[1], acc[2], acc[3]};
}

// ---------------------------------------------------------------------------
// One-pass scores + online-softmax partial context. grid (NCHUNK, B),
// 256 threads (4 waves), wave owns RPW rows; 2-row batch + depth-1 prefetch,
// branchless rescale, nontemporal enc loads.
// ---------------------------------------------------------------------------
__global__ __launch_bounds__(256, 4) void attn_partial(
    const float* __restrict__ enc, const float* __restrict__ qp,
    float* __restrict__ part_ctx, float* __restrict__ part_ml,
    float* __restrict__ scores_raw)
{
    __shared__ float q_lds[HH];
    __shared__ float ctx_lds[4][HH];
    __shared__ float ml_lds[4][2];

    const int t = threadIdx.x;
    const int c = blockIdx.x;
    const int b = blockIdx.y;

    {   // q = sum of 4 K-split partials (one f4 per thread: 256*4 = 1024)
        const f4 v = ((const f4*)(qp + (size_t)b * HH))[t]
                   + ((const f4*)(qp + 65536 + (size_t)b * HH))[t]
                   + ((const f4*)(qp + 131072 + (size_t)b * HH))[t]
                   + ((const f4*)(qp + 196608 + (size_t)b * HH))[t];
        ((f4*)q_lds)[t] = v;
    }
    __syncthreads();

    const int w    = t >> 6;
    const int lane = t & 63;
    const size_t RS = (size_t)BB * HH;  // floats per s-step
    const float* rp = enc + ((size_t)(c * CHUNK + w * RPW) * BB + b) * HH + 4 * lane;

    f4 cur0[4], cur1[4], nxt0[4], nxt1[4];
    #pragma unroll
    for (int k = 0; k < 4; ++k) {
        cur0[k] = __builtin_nontemporal_load((const f4*)(rp + k * 256));
        cur1[k] = __builtin_nontemporal_load((const f4*)(rp + RS + k * 256));
    }

    float m = -INFINITY, lsum = 0.f;
    f4 ctxv[4];
    #pragma unroll
    for (int k = 0; k < 4; ++k) ctxv[k] = (f4)0.f;

    #pragma unroll
    for (int r = 0; r < RPW; r += 2) {
        if (r + 2 < RPW) {
            const float* np = rp + 2 * RS;
            #pragma unroll
            for (int k = 0; k < 4; ++k) {
                nxt0[k] = __builtin_nontemporal_load((const f4*)(np + k * 256));
                nxt1[k] = __builtin_nontemporal_load((const f4*)(np + RS + k * 256));
            }
        }
        float d0 = 0.f, d1 = 0.f;
        #pragma unroll
        for (int k = 0; k < 4; ++k) {
            const f4 qv = *(const f4*)(q_lds + k * 256 + 4 * lane);
            d0 += cur0[k].x * qv.x + cur0[k].y * qv.y + cur0[k].z * qv.z + cur0[k].w * qv.w;
            d1 += cur1[k].x * qv.x + cur1[k].y * qv.y + cur1[k].z * qv.z + cur1[k].w * qv.w;
        }
        #pragma unroll
        for (int off = 32; off; off >>= 1) {
            d0 += __shfl_xor(d0, off, 64);
            d1 += __shfl_xor(d1, off, 64);
        }
        if (lane == 0) {
            const int s = c * CHUNK + w * RPW + r;
            scores_raw[b * SS + s]     = d0;
            scores_raw[b * SS + s + 1] = d1;
        }
        const float mx = fmaxf(d0, d1);
        const float nm = fmaxf(m, mx);
        const float sc = expf(m - nm);          // 1 if no new max; 0 on first iter
        const float p0 = expf(d0 - nm);
        const float p1 = expf(d1 - nm);
        lsum = lsum * sc + p0 + p1;
        m = nm;
        #pragma unroll
        for (int k = 0; k < 4; ++k)
            ctxv[k] = ctxv[k] * sc + p0 * cur0[k] + p1 * cur1[k];
        if (r + 2 < RPW) {
            #pragma unroll
            for (int k = 0; k < 4; ++k) { cur0[k] = nxt0[k]; cur1[k] = nxt1[k]; }
            rp += 2 * RS;
        }
    }

    if (lane == 0) { ml_lds[w][0] = m; ml_lds[w][1] = lsum; }
    #pragma unroll
    for (int k = 0; k < 4; ++k)
        *(f4*)&ctx_lds[w][k * 256 + 4 * lane] = ctxv[k];
    __syncthreads();

    const float m0 = ml_lds[0][0], m1 = ml_lds[1][0], m2 = ml_lds[2][0], m3 = ml_lds[3][0];
    const float mb = fmaxf(fmaxf(m0, m1), fmaxf(m2, m3));
    const float f0 = expf(m0 - mb), f1 = expf(m1 - mb), f2 = expf(m2 - mb), f3 = expf(m3 - mb);
    const float lb = f0 * ml_lds[0][1] + f1 * ml_lds[1][1] + f2 * ml_lds[2][1] + f3 * ml_lds[3][1];

    const f4 a0 = ((const f4*)&ctx_lds[0][0])[t];
    const f4 a1 = ((const f4*)&ctx_lds[1][0])[t];
    const f4 a2 = ((const f4*)&ctx_lds[2][0])[t];
    const f4 a3 = ((const f4*)&ctx_lds[3][0])[t];
    const f4 o = f0 * a0 + f1 * a1 + f2 * a2 + f3 * a3;
    ((f4*)(part_ctx + ((size_t)(b * NCHUNK + c)) * HH))[t] = o;
    if (t == 0) {
        part_ml[(b * NCHUNK + c) * 2 + 0] = mb;
        part_ml[(b * NCHUNK + c) * 2 + 1] = lb;
    }
}

// ---------------------------------------------------------------------------
// Combine NCHUNK partials -> ctx_final; normalize weights in place.
// grid (B, 4): each block does an H-quarter of ctx + 512 of the 2048 weights.
// ---------------------------------------------------------------------------
__global__ __launch_bounds__(256) void attn_combine(
    const float* __restrict__ part_ctx, const float* __restrict__ part_ml,
    float* __restrict__ ctx_final, float* __restrict__ wts)
{
    const int b = blockIdx.x, quad = blockIdx.y, t = threadIdx.x;
    __shared__ float mls[NCHUNK * 2];
    if (t < NCHUNK * 2) mls[t] = part_ml[b * NCHUNK * 2 + t];
    __syncthreads();

    float M = -INFINITY;
    #pragma unroll
    for (int cc = 0; cc < NCHUNK; ++cc) M = fmaxf(M, mls[2 * cc]);
    float L = 0.f;
    float f[NCHUNK];
    #pragma unroll
    for (int cc = 0; cc < NCHUNK; ++cc) {
        f[cc] = expf(mls[2 * cc] - M);
        L += f[cc] * mls[2 * cc + 1];
    }
    const float inv = 1.0f / L;

    if (t < 64) {
        f4 acc = (f4)0.f;
        #pragma unroll
        for (int cc = 0; cc < NCHUNK; ++cc) {
            const f4 v = ((const f4*)(part_ctx + ((size_t)(b * NCHUNK + cc)) * HH + quad * 256))[t];
            acc += f[cc] * v;
        }
        ((f4*)(ctx_final + (size_t)b * HH + quad * 256))[t] = acc * inv;
    }
    const int s0 = quad * 512 + 2 * t;
    const float w0 = wts[b * SS + s0], w1 = wts[b * SS + s0 + 1];
    wts[b * SS + s0]     = expf(w0 - M) * inv;
    wts[b * SS + s0 + 1] = expf(w1 - M) * inv;
}

// ---------------------------------------------------------------------------
// Sum 8 K-split partials + tanh -> context output. grid 64, 256 thr, f4 each.
// ---------------------------------------------------------------------------
__global__ __launch_bounds__(256) void gemm2_combine(
    const float* __restrict__ op, float* __restrict__ out)
{
    const int i = blockIdx.x * 256 + threadIdx.x;  // f4 index over 16384
    f4 a = (f4)0.f;
    #pragma unroll
    for (int sp = 0; sp < 8; ++sp)
        a += ((const f4*)(op + (size_t)sp * BB * HH))[i];
    f4 r;
    r.x = tanhf(a.x); r.y = tanhf(a.y); r.z = tanhf(a.z); r.w = tanhf(a.w);
    ((f4*)out)[i] = r;
}

extern "C" void kernel_launch(void* const* d_in, const int* in_sizes, int n_in,
                              void* d_out, int out_size, void* d_ws, size_t ws_size,
                              hipStream_t stream)
{
    const float* dec   = (const float*)d_in[0];  // [B,H]
    const float* enc   = (const float*)d_in[1];  // [S,B,H]
    const float* W_a   = (const float*)d_in[2];  // [H,H]
    const float* W_out = (const float*)d_in[3];  // [H,2H]
    float* out = (float*)d_out;                  // [B*H] context, then [B*S] weights
    float* ws  = (float*)d_ws;

    float* q_part    = ws + QP_OFF;
    float* part_ctx  = ws + PCTX_OFF;
    float* part_ml   = ws + PML_OFF;
    float* ctx_final = ws + CTXF_OFF;
    float* o_part    = ws + OP_OFF;
    float* wts       = out + BB * HH;

    // 1) q partials: q = dec @ W_a^T, K-split x4
    gemm_cols16<<<dim3(64, 4), 256, 0, stream>>>(dec, dec, W_a, q_part, 1024, 2);
    // 2) one-pass scores + online-softmax partial context (sums q partials)
    attn_partial<<<dim3(NCHUNK, BB), 256, 0, stream>>>(enc, q_part, part_ctx, part_ml, wts);
    // 3) combine partials, normalize weights in place
    attn_combine<<<dim3(BB, 4), 256, 0, stream>>>(part_ctx, part_ml, ctx_final, wts);
    // 4) out partials: tanh-GEMM K-split x8 over concat(ctx, dec)
    gemm_cols16<<<dim3(64, 8), 256, 0, stream>>>(ctx_final, dec, W_out, o_part, 2048, 2);
    // 5) sum partials + tanh
    gemm2_combine<<<64, 256, 0, stream>>>(o_part, out);
}

// Round 3
// 201.736 us; speedup vs baseline: 1.4891x; 1.4891x over previous
//
#include <hip/hip_runtime.h>
#include <math.h>

#define BB 64
#define SS 2048
#define HH 1024
#define NCHUNK 16
#define CHUNK 128   // rows per block
#define TILE 16     // rows per LDS tile
#define NT (CHUNK / TILE)  // 8 tiles

typedef float f4 __attribute__((ext_vector_type(4)));

// ws layout (floats):
#define Q_OFF    0
#define PCTX_OFF (BB * HH)
#define PML_OFF  (PCTX_OFF + BB * NCHUNK * HH)
#define CTXF_OFF (PML_OFF + BB * NCHUNK * 2)
// total = CTXF_OFF + BB*HH ~= 4.7 MB

__device__ __forceinline__ void gll16(const float* gsrc, float* ldst) {
    __builtin_amdgcn_global_load_lds(
        (const __attribute__((address_space(1))) void*)gsrc,
        (__attribute__((address_space(3))) void*)ldst, 16, 0, 0);
}

// ---------------------------------------------------------------------------
// R1 gemm64 (verbatim): out[b][i] = act( sum_j A(b,j) * W[i*K + j] )
// ---------------------------------------------------------------------------
__global__ __launch_bounds__(256) void gemm64(
    const float* __restrict__ A0, const float* __restrict__ A1,
    const float* __restrict__ W, float* __restrict__ out,
    int nchunks, int do_tanh)
{
    __shared__ float A_lds[64 * 256];
    __shared__ float W_lds[4 * 256];
    const int t  = threadIdx.x;
    const int it = blockIdx.x;
    const int b  = t & 63;
    const int il = t >> 6;
    const int K  = nchunks << 8;
    float acc = 0.f;

    for (int kc = 0; kc < nchunks; ++kc) {
        for (int idx = t; idx < 64 * 64; idx += 256) {
            const int row = idx >> 6;
            const int g   = idx & 63;
            const float* src = (kc < 4) ? (A0 + row * 1024 + kc * 256)
                                        : (A1 + row * 1024 + (kc - 4) * 256);
            float4 v = *(const float4*)(src + g * 4);
            ((float4*)A_lds)[row * 64 + (g ^ row)] = v;
        }
        for (int idx = t; idx < 1024; idx += 256) {
            const int r2 = idx >> 8;
            const int cc = idx & 255;
            W_lds[idx] = W[(size_t)(it * 4 + r2) * K + kc * 256 + cc];
        }
        __syncthreads();
        #pragma unroll 8
        for (int j4 = 0; j4 < 64; ++j4) {
            float4 a  = ((const float4*)A_lds)[b * 64 + (j4 ^ b)];
            float4 wv = ((const float4*)W_lds)[il * 64 + j4];
            acc += a.x * wv.x + a.y * wv.y + a.z * wv.z + a.w * wv.w;
        }
        __syncthreads();
    }
    if (do_tanh) acc = tanhf(acc);
    out[b * 1024 + it * 4 + il] = acc;
}

// ---------------------------------------------------------------------------
// attn_tile: per (chunk c, batch b) block. 4 waves; each wave stages ITS OWN
// 4 rows of each 16-row tile via global_load_lds into a double-buffered
// 128 KB LDS region, counted vmcnt(16), no barriers in the main loop.
// 4-row-batched dot + butterfly reduce + branchless online softmax.
// ---------------------------------------------------------------------------
__global__ __launch_bounds__(256) void attn_tile(
    const float* __restrict__ enc, const float* __restrict__ q,
    float* __restrict__ part_ctx, float* __restrict__ part_ml,
    float* __restrict__ scores_raw)
{
    __shared__ float smem[2 * TILE * HH];  // 128 KB double buffer
    const int t    = threadIdx.x;
    const int c    = blockIdx.x;
    const int b    = blockIdx.y;
    const int w    = t >> 6;
    const int lane = t & 63;

    // q fragment held in registers (q is L2-hot, 16 floats/lane)
    f4 qreg[4];
    #pragma unroll
    for (int k = 0; k < 4; ++k)
        qreg[k] = *(const f4*)(q + (size_t)b * HH + k * 256 + 4 * lane);

    const size_t RS = (size_t)BB * HH;           // floats between s and s+1
    const float* enc_b = enc + (size_t)b * HH + 4 * lane;

    // prologue: stage tile 0 (wave w stages rows 4w..4w+3)
    {
        const int s0 = c * CHUNK + w * 4;
        #pragma unroll
        for (int i = 0; i < 16; ++i) {
            const int r = i >> 2, seg = i & 3;
            gll16(enc_b + (size_t)(s0 + r) * RS + seg * 256,
                  smem + (w * 4 + r) * HH + seg * 256);
        }
    }

    float m = -INFINITY, lsum = 0.f;
    f4 ctxv[4];
    #pragma unroll
    for (int k = 0; k < 4; ++k) ctxv[k] = (f4)0.f;

    #pragma unroll 2
    for (int tt = 0; tt < NT; ++tt) {
        // issue prefetch of tile tt+1 into the other buffer, then wait for
        // tile tt only (counted vmcnt: 16 newest stay in flight)
        if (tt + 1 < NT) {
            float* buf_n = smem + ((tt + 1) & 1) * TILE * HH;
            const int s0 = c * CHUNK + (tt + 1) * TILE + w * 4;
            #pragma unroll
            for (int i = 0; i < 16; ++i) {
                const int r = i >> 2, seg = i & 3;
                gll16(enc_b + (size_t)(s0 + r) * RS + seg * 256,
                      buf_n + (w * 4 + r) * HH + seg * 256);
            }
            asm volatile("s_waitcnt vmcnt(16)" ::: "memory");
        } else {
            asm volatile("s_waitcnt vmcnt(0)" ::: "memory");
        }
        __builtin_amdgcn_sched_barrier(0);

        const float* buf = smem + (tt & 1) * TILE * HH;
        f4 v[4][4];
        #pragma unroll
        for (int r = 0; r < 4; ++r)
            #pragma unroll
            for (int k = 0; k < 4; ++k)
                v[r][k] = *(const f4*)(buf + (w * 4 + r) * HH + k * 256 + 4 * lane);

        float d[4];
        #pragma unroll
        for (int r = 0; r < 4; ++r) {
            f4 s = v[r][0] * qreg[0];
            s += v[r][1] * qreg[1];
            s += v[r][2] * qreg[2];
            s += v[r][3] * qreg[3];
            d[r] = s.x + s.y + s.z + s.w;
        }
        // 4-wide butterfly reduce (6 serial steps, 4-way ILP)
        #pragma unroll
        for (int off = 32; off; off >>= 1) {
            #pragma unroll
            for (int r = 0; r < 4; ++r)
                d[r] += __shfl_xor(d[r], off, 64);
        }

        // raw scores: one masked store per tile per wave
        const int sbase = c * CHUNK + tt * TILE + w * 4;
        float sv = d[0];
        sv = (lane == 1) ? d[1] : sv;
        sv = (lane == 2) ? d[2] : sv;
        sv = (lane == 3) ? d[3] : sv;
        if (lane < 4) scores_raw[b * SS + sbase + lane] = sv;

        // branchless online softmax update over 4 rows
        const float mx = fmaxf(fmaxf(d[0], d[1]), fmaxf(d[2], d[3]));
        const float nm = fmaxf(m, mx);
        const float sc = expf(m - nm);   // 0 on first tile (m = -inf)
        float p[4];
        #pragma unroll
        for (int r = 0; r < 4; ++r) p[r] = expf(d[r] - nm);
        lsum = lsum * sc + p[0] + p[1] + p[2] + p[3];
        m = nm;
        #pragma unroll
        for (int k = 0; k < 4; ++k)
            ctxv[k] = ctxv[k] * sc
                    + p[0] * v[0][k] + p[1] * v[1][k]
                    + p[2] * v[2][k] + p[3] * v[3][k];
    }

    // merge the 4 waves' (m, l, ctx) — reuse smem (staging complete)
    __syncthreads();
    float* ctx_m = smem;            // 4 * 1024 floats
    float* ml_m  = smem + 4 * HH;   // 8 floats
    if (lane == 0) { ml_m[w * 2] = m; ml_m[w * 2 + 1] = lsum; }
    #pragma unroll
    for (int k = 0; k < 4; ++k)
        *(f4*)(ctx_m + w * HH + k * 256 + 4 * lane) = ctxv[k];
    __syncthreads();

    const float m0 = ml_m[0], l0 = ml_m[1], m1 = ml_m[2], l1 = ml_m[3];
    const float m2 = ml_m[4], l2 = ml_m[5], m3 = ml_m[6], l3 = ml_m[7];
    const float mb = fmaxf(fmaxf(m0, m1), fmaxf(m2, m3));
    const float f0 = expf(m0 - mb), f1 = expf(m1 - mb);
    const float f2 = expf(m2 - mb), f3 = expf(m3 - mb);
    const float lb = f0 * l0 + f1 * l1 + f2 * l2 + f3 * l3;

    const f4 a0 = ((const f4*)(ctx_m + 0 * HH))[t];
    const f4 a1 = ((const f4*)(ctx_m + 1 * HH))[t];
    const f4 a2 = ((const f4*)(ctx_m + 2 * HH))[t];
    const f4 a3 = ((const f4*)(ctx_m + 3 * HH))[t];
    const f4 o = f0 * a0 + f1 * a1 + f2 * a2 + f3 * a3;
    ((f4*)(part_ctx + ((size_t)b * NCHUNK + c) * HH))[t] = o;
    if (t == 0) {
        part_ml[(b * NCHUNK + c) * 2 + 0] = mb;
        part_ml[(b * NCHUNK + c) * 2 + 1] = lb;
    }
}

// ---------------------------------------------------------------------------
// R1 attn_combine (verbatim, NCHUNK=16)
// ---------------------------------------------------------------------------
__global__ __launch_bounds__(256) void attn_combine(
    const float* __restrict__ part_ctx, const float* __restrict__ part_ml,
    float* __restrict__ ctx_final, float* __restrict__ wts)
{
    const int b = blockIdx.x;
    const int t = threadIdx.x;
    __shared__ float mls[NCHUNK][2];
    for (int i = t; i < NCHUNK * 2; i += 256)
        ((float*)mls)[i] = part_ml[b * NCHUNK * 2 + i];
    __syncthreads();

    float M = -INFINITY;
    #pragma unroll
    for (int c2 = 0; c2 < NCHUNK; ++c2) M = fmaxf(M, mls[c2][0]);
    float f[NCHUNK];
    float L = 0.f;
    #pragma unroll
    for (int c2 = 0; c2 < NCHUNK; ++c2) {
        f[c2] = expf(mls[c2][0] - M);
        L += f[c2] * mls[c2][1];
    }
    const float inv = 1.0f / L;

    float4 acc = make_float4(0.f, 0.f, 0.f, 0.f);
    #pragma unroll
    for (int c2 = 0; c2 < NCHUNK; ++c2) {
        float4 v = ((const float4*)(part_ctx + ((size_t)b * NCHUNK + c2) * HH))[t];
        acc.x += f[c2] * v.x; acc.y += f[c2] * v.y;
        acc.z += f[c2] * v.z; acc.w += f[c2] * v.w;
    }
    acc.x *= inv; acc.y *= inv; acc.z *= inv; acc.w *= inv;
    ((float4*)(ctx_final + (size_t)b * HH))[t] = acc;

    for (int s = t; s < SS; s += 256)
        wts[b * SS + s] = expf(wts[b * SS + s] - M) * inv;
}

extern "C" void kernel_launch(void* const* d_in, const int* in_sizes, int n_in,
                              void* d_out, int out_size, void* d_ws, size_t ws_size,
                              hipStream_t stream)
{
    const float* dec   = (const float*)d_in[0];  // [B,H]
    const float* enc   = (const float*)d_in[1];  // [S,B,H]
    const float* W_a   = (const float*)d_in[2];  // [H,H]
    const float* W_out = (const float*)d_in[3];  // [H,2H]
    float* out = (float*)d_out;                  // [B*H] context, then [B*S] weights
    float* ws  = (float*)d_ws;

    float* q         = ws + Q_OFF;
    float* part_ctx  = ws + PCTX_OFF;
    float* part_ml   = ws + PML_OFF;
    float* ctx_final = ws + CTXF_OFF;
    float* wts       = out + BB * HH;

    // 1) q = dec @ W_a^T
    gemm64<<<256, 256, 0, stream>>>(dec, dec, W_a, q, 4, 0);
    // 2) one-pass scores + online-softmax partial context (LDS-staged, dbuf)
    attn_tile<<<dim3(NCHUNK, BB), 256, 0, stream>>>(enc, q, part_ctx, part_ml, wts);
    // 3) combine partials, normalize weights in place
    attn_combine<<<BB, 256, 0, stream>>>(part_ctx, part_ml, ctx_final, wts);
    // 4) out = tanh(concat(ctx, dec) @ W_out^T)
    gemm64<<<256, 256, 0, stream>>>(ctx_final, dec, W_out, out, 8, 1);
}